// Round 5
// baseline (257.750 us; speedup 1.0000x reference)
//
#include <hip/hip_runtime.h>

typedef __bf16 bf16_8 __attribute__((ext_vector_type(8)));
typedef __bf16 bf16_4 __attribute__((ext_vector_type(4)));
typedef float  f32x4  __attribute__((ext_vector_type(4)));

#define NB 32
#define NT 2048
#define NC 384
#define NH 64

static __device__ __forceinline__ f32x4 mfma16(bf16_8 a, bf16_8 b, f32x4 c) {
  return __builtin_amdgcn_mfma_f32_16x16x32_bf16(a, b, c, 0, 0, 0);
}

// ---- kernel 1: pack weights: fp32 [C,H] x3 -> bf16 Wt[n][k], n: 0-63=Q, 64-127=K, 128-191=V
// Q gets 0.125*log2(e) folded in: attention softmax then runs in exp2 domain.
__global__ void pack_w_kernel(const float* __restrict__ Wk, const float* __restrict__ Wq,
                              const float* __restrict__ Wv, __bf16* __restrict__ Wt) {
  int idx = blockIdx.x * 256 + threadIdx.x;
  if (idx >= 192 * NC) return;
  int n = idx / NC, k = idx % NC;
  int sel = n >> 6, h = n & 63;
  const float* W = (sel == 0) ? Wq : (sel == 1 ? Wk : Wv);
  float v = W[k * NH + h];
  if (sel == 0) v *= 0.125f * 1.44269504088896f;  // H^-0.5 * log2(e)
  Wt[idx] = (__bf16)v;
}

// ---- kernel 2: QKV projection, entire Wt in LDS (XOR-swizzled), x prefetched 4 deep.
__launch_bounds__(1024, 4)
__global__ void qkv_kernel(const float* __restrict__ x, const __bf16* __restrict__ Wt,
                           __bf16* __restrict__ Q, __bf16* __restrict__ K,
                           __bf16* __restrict__ Vt) {
  __shared__ __bf16 Wl[192 * 384];  // 147,456 B; chunk c of row r stored at c^(r&7)

  const int tid  = threadIdx.x;
  const int lane = tid & 63, wq = tid >> 6;
  const int quad = lane >> 4, l16 = lane & 15;
  const int rowblk = blockIdx.x * 256;
  const int rbase  = rowblk + wq * 16;
  const int row    = rbase + l16;

  // stage Wt -> LDS, 16-B chunks, XOR swizzle
  #pragma unroll
  for (int i = 0; i < 9; ++i) {
    int g = tid + i * 1024;
    int r = g / 48, c = g - r * 48;
    int p = c ^ (r & 7);
    uint4 v = ((const uint4*)Wt)[g];
    *(uint4*)&Wl[(r * 48 + p) * 8] = v;
  }
  __syncthreads();

  f32x4 acc[12];
  #pragma unroll
  for (int n = 0; n < 12; ++n) acc[n] = f32x4{0.f, 0.f, 0.f, 0.f};

  const float* xrow = x + (size_t)row * NC;
  f32x4 xp0[4], xp1[4];
  #pragma unroll
  for (int d = 0; d < 4; ++d) {  // 4-deep prefetch pipeline
    xp0[d] = *(const f32x4*)(xrow + d * 32 + quad * 8);
    xp1[d] = *(const f32x4*)(xrow + d * 32 + quad * 8 + 4);
  }

  #pragma unroll
  for (int kc = 0; kc < 12; ++kc) {
    const int slot = kc & 3;
    bf16_8 a;
    a[0] = (__bf16)xp0[slot][0]; a[1] = (__bf16)xp0[slot][1];
    a[2] = (__bf16)xp0[slot][2]; a[3] = (__bf16)xp0[slot][3];
    a[4] = (__bf16)xp1[slot][0]; a[5] = (__bf16)xp1[slot][1];
    a[6] = (__bf16)xp1[slot][2]; a[7] = (__bf16)xp1[slot][3];
    if (kc + 4 < 12) {  // refill slot, 4 iterations ahead
      const float* xp = xrow + (kc + 4) * 32 + quad * 8;
      xp0[slot] = *(const f32x4*)xp;
      xp1[slot] = *(const f32x4*)(xp + 4);
    }
    const int pc = (kc * 4 + quad) ^ (l16 & 7);
    const int cbase = l16 * 48 + pc;
    #pragma unroll
    for (int n = 0; n < 12; ++n) {
      bf16_8 b = *(const bf16_8*)&Wl[(n * 16 * 48 + cbase) * 8];
      acc[n] = mfma16(a, b, acc[n]);
    }
  }

  // Q, K direct stores (C-layout: row=quad*4+r, col=l16)
  #pragma unroll
  for (int n = 0; n < 8; ++n)
    #pragma unroll
    for (int r = 0; r < 4; ++r) {
      int orow = rbase + quad * 4 + r;
      int h = (n & 3) * 16 + l16;
      __bf16 bv = (__bf16)acc[n][r];
      if (n < 4) Q[(size_t)orow * NH + h] = bv;
      else       K[(size_t)orow * NH + h] = bv;
    }

  // V transpose via reused W LDS region
  __syncthreads();
  __bf16 (*Vl)[264] = (__bf16(*)[264])Wl;  // [h][t_local 256 + pad8]
  #pragma unroll
  for (int n = 8; n < 12; ++n) {
    int h = (n - 8) * 16 + l16;
    int t0 = wq * 16 + quad * 4;
    bf16_4 p;
    p[0] = (__bf16)acc[n][0]; p[1] = (__bf16)acc[n][1];
    p[2] = (__bf16)acc[n][2]; p[3] = (__bf16)acc[n][3];
    *(bf16_4*)&Vl[h][t0] = p;
  }
  __syncthreads();
  {
    int h = tid >> 4, seg = tid & 15;
    int bb = rowblk >> 11, t0 = (rowblk & (NT - 1)) + seg * 16;
    const __bf16* src = &Vl[h][seg * 16];
    __bf16* dst = Vt + ((size_t)(bb * NH + h)) * NT + t0;
    ((uint4*)dst)[0] = ((const uint4*)src)[0];
    ((uint4*)dst)[1] = ((const uint4*)src)[1];
  }
}

// ---- kernel 3: flash attention, fold-paired, BN=128 per super-iteration.
// 17 super-iters per block (balanced). Single K/V buffer, 2 barriers/super,
// next tile's global loads issued before compute so they fly across both barriers.
__launch_bounds__(256, 2)
__global__ void attn_kernel(const __bf16* __restrict__ Q, const __bf16* __restrict__ K,
                            const __bf16* __restrict__ Vt, float* __restrict__ out) {
  __shared__ __bf16 Ks[128][72];     // [s][h]
  __shared__ __bf16 Vs[64][136];     // [h][s]
  __shared__ __bf16 Ps[4][16][136];  // per-wave P[q][s 128]

  const int tid  = threadIdx.x;
  const int lane = tid & 63, wq = tid >> 6;
  const int quad = lane >> 4, l16 = lane & 15;
  const int b    = blockIdx.x >> 4;
  const int pair = blockIdx.x & 15;

  const float NEG_INF = -__builtin_inff();
  // staging split: K tile 128x64 (2 thr/row, 64B each), V tile 64x128 (4 thr/row)
  const int kr = tid >> 1, kc4 = (tid & 1) * 32;
  const int vr = tid >> 2, vc  = (tid & 3) * 32;
  const __bf16* Kg = K  + (size_t)b * NT * NH;
  const __bf16* Vg = Vt + (size_t)b * NH * NT;

  for (int pass = 0; pass < 2; ++pass) {
    const int qt = pass ? pair : (31 - pair);
    const int q0 = qt * 64;
    const int nSuper = (qt + 2) >> 1;  // ceil((qt+1)*64 / 128)

    const __bf16* qrow = Q + ((size_t)(b * NT + q0 + wq * 16 + l16)) * NH + quad * 8;
    bf16_8 qf0 = *(const bf16_8*)qrow;
    bf16_8 qf1 = *(const bf16_8*)(qrow + 32);

    f32x4 o[4];
    #pragma unroll
    for (int i = 0; i < 4; ++i) o[i] = f32x4{0.f, 0.f, 0.f, 0.f};
    float m_i = NEG_INF, l_i = 0.f;

    // prologue: stage super-tile 0 (prev pass's readers all done at its last barrier)
    {
      const uint4* kp = (const uint4*)(Kg + (size_t)kr * NH + kc4);
      const uint4* vp = (const uint4*)(Vg + (size_t)vr * NT + vc);
      uint4 pk0 = kp[0], pk1 = kp[1], pk2 = kp[2], pk3 = kp[3];
      uint4 pv0 = vp[0], pv1 = vp[1], pv2 = vp[2], pv3 = vp[3];
      *(uint4*)&Ks[kr][kc4]      = pk0; *(uint4*)&Ks[kr][kc4 + 8]  = pk1;
      *(uint4*)&Ks[kr][kc4 + 16] = pk2; *(uint4*)&Ks[kr][kc4 + 24] = pk3;
      *(uint4*)&Vs[vr][vc]       = pv0; *(uint4*)&Vs[vr][vc + 8]   = pv1;
      *(uint4*)&Vs[vr][vc + 16]  = pv2; *(uint4*)&Vs[vr][vc + 24]  = pv3;
    }

    for (int i = 0; i < nSuper; ++i) {
      const bool more = (i + 1 < nSuper);
      uint4 pk[4], pv[4];
      if (more) {  // issue next super-tile's loads; in flight across both barriers
        const int s0n = (i + 1) * 128;
        const uint4* kp = (const uint4*)(Kg + (size_t)(s0n + kr) * NH + kc4);
        pk[0] = kp[0]; pk[1] = kp[1]; pk[2] = kp[2]; pk[3] = kp[3];
        const uint4* vp = (const uint4*)(Vg + (size_t)vr * NT + s0n + vc);
        pv[0] = vp[0]; pv[1] = vp[1]; pv[2] = vp[2]; pv[3] = vp[3];
      }
      __syncthreads();  // current super-tile fully staged

      // S^T: A=K rows (m=s), B=Q^T (n=q). 8 s-subtiles of 16.
      f32x4 sv[8];
      #pragma unroll
      for (int st = 0; st < 8; ++st) {
        bf16_8 a0 = *(const bf16_8*)&Ks[st * 16 + l16][quad * 8];
        bf16_8 a1 = *(const bf16_8*)&Ks[st * 16 + l16][quad * 8 + 32];
        f32x4 accv = f32x4{0.f, 0.f, 0.f, 0.f};
        accv = mfma16(a0, qf0, accv);
        accv = mfma16(a1, qf1, accv);
        sv[st] = accv;
      }

      if (i == nSuper - 1) {  // diagonal super-tile: causal mask (s beyond qt also killed here)
        int slimit = q0 + wq * 16 + l16 - i * 128;  // local s must be <= slimit
        #pragma unroll
        for (int st = 0; st < 8; ++st)
          #pragma unroll
          for (int rr = 0; rr < 4; ++rr) {
            int sloc = st * 16 + quad * 4 + rr;
            if (sloc > slimit) sv[st][rr] = NEG_INF;
          }
      }

      // online softmax in exp2 domain (log2e pre-folded into Wq)
      float mx = NEG_INF;
      #pragma unroll
      for (int st = 0; st < 8; ++st)
        #pragma unroll
        for (int rr = 0; rr < 4; ++rr) mx = fmaxf(mx, sv[st][rr]);
      mx = fmaxf(mx, __shfl_xor(mx, 16));
      mx = fmaxf(mx, __shfl_xor(mx, 32));
      float m_new = fmaxf(m_i, mx);
      float alpha = __builtin_amdgcn_exp2f(m_i - m_new);

      float lsum = 0.f;
      #pragma unroll
      for (int st = 0; st < 8; ++st) {
        bf16_4 pkv;
        #pragma unroll
        for (int rr = 0; rr < 4; ++rr) {
          float p = __builtin_amdgcn_exp2f(sv[st][rr] - m_new);
          lsum += p;
          pkv[rr] = (__bf16)p;
        }
        *(bf16_4*)&Ps[wq][l16][st * 16 + quad * 4] = pkv;
      }
      lsum += __shfl_xor(lsum, 16);
      lsum += __shfl_xor(lsum, 32);
      l_i = l_i * alpha + lsum;
      m_i = m_new;

      // rescale O (C-layout row q = quad*4+rr)
      f32x4 av;
      #pragma unroll
      for (int rr = 0; rr < 4; ++rr) av[rr] = __shfl(alpha, quad * 4 + rr);
      #pragma unroll
      for (int nt = 0; nt < 4; ++nt)
        #pragma unroll
        for (int rr = 0; rr < 4; ++rr) o[nt][rr] *= av[rr];

      // PV over k=128: A = P (own wave's Ps), B = V
      bf16_8 pa[4];
      #pragma unroll
      for (int c = 0; c < 4; ++c)
        pa[c] = *(const bf16_8*)&Ps[wq][l16][c * 32 + quad * 8];
      #pragma unroll
      for (int nt = 0; nt < 4; ++nt) {
        #pragma unroll
        for (int c = 0; c < 4; ++c) {
          bf16_8 bv = *(const bf16_8*)&Vs[nt * 16 + l16][c * 32 + quad * 8];
          o[nt] = mfma16(pa[c], bv, o[nt]);
        }
      }

      __syncthreads();  // all readers done with current super-tile
      if (more) {
        *(uint4*)&Ks[kr][kc4]      = pk[0]; *(uint4*)&Ks[kr][kc4 + 8]  = pk[1];
        *(uint4*)&Ks[kr][kc4 + 16] = pk[2]; *(uint4*)&Ks[kr][kc4 + 24] = pk[3];
        *(uint4*)&Vs[vr][vc]       = pv[0]; *(uint4*)&Vs[vr][vc + 8]   = pv[1];
        *(uint4*)&Vs[vr][vc + 16]  = pv[2]; *(uint4*)&Vs[vr][vc + 24]  = pv[3];
      }
    }

    // epilogue: divide by l, store fp32
    f32x4 lv;
    #pragma unroll
    for (int rr = 0; rr < 4; ++rr) lv[rr] = 1.f / __shfl(l_i, quad * 4 + rr);
    float* op = out + ((size_t)(b * NT + q0 + wq * 16 + quad * 4)) * NH + l16;
    #pragma unroll
    for (int nt = 0; nt < 4; ++nt)
      #pragma unroll
      for (int rr = 0; rr < 4; ++rr)
        op[(size_t)rr * NH + nt * 16] = o[nt][rr] * lv[rr];
  }
}

extern "C" void kernel_launch(void* const* d_in, const int* in_sizes, int n_in,
                              void* d_out, int out_size, void* d_ws, size_t ws_size,
                              hipStream_t stream) {
  const float* x  = (const float*)d_in[0];
  const float* Wk = (const float*)d_in[1];
  const float* Wq = (const float*)d_in[2];
  const float* Wv = (const float*)d_in[3];
  float* out = (float*)d_out;

  char* ws = (char*)d_ws;
  __bf16* Wt  = (__bf16*)ws;                       // 192*384*2 = 147,456 B
  __bf16* Qb  = (__bf16*)(ws + 256 * 1024);        // each 32*2048*64*2 = 8 MiB
  __bf16* Kb  = Qb + (size_t)NB * NT * NH;
  __bf16* Vtb = Kb + (size_t)NB * NT * NH;

  pack_w_kernel<<<288, 256, 0, stream>>>(Wk, Wq, Wv, Wt);
  qkv_kernel<<<256, 1024, 0, stream>>>(x, Wt, Qb, Kb, Vtb);
  attn_kernel<<<NB * 16, 256, 0, stream>>>(Qb, Kb, Vtb, out);
}

// Round 6
// 239.650 us; speedup vs baseline: 1.0755x; 1.0755x over previous
//
#include <hip/hip_runtime.h>

typedef __bf16 bf16_8 __attribute__((ext_vector_type(8)));
typedef __bf16 bf16_4 __attribute__((ext_vector_type(4)));
typedef float  f32x4  __attribute__((ext_vector_type(4)));

#define NB 32
#define NT 2048
#define NC 384
#define NH 64

static __device__ __forceinline__ f32x4 mfma16(bf16_8 a, bf16_8 b, f32x4 c) {
  return __builtin_amdgcn_mfma_f32_16x16x32_bf16(a, b, c, 0, 0, 0);
}

// ---- kernel 1: pack weights: fp32 [C,H] x3 -> bf16 Wt[n][k], n: 0-63=Q, 64-127=K, 128-191=V
// Q gets 0.125*log2(e) folded in: attention softmax then runs in exp2 domain.
__global__ void pack_w_kernel(const float* __restrict__ Wk, const float* __restrict__ Wq,
                              const float* __restrict__ Wv, __bf16* __restrict__ Wt) {
  int idx = blockIdx.x * 256 + threadIdx.x;
  if (idx >= 192 * NC) return;
  int n = idx / NC, k = idx % NC;
  int sel = n >> 6, h = n & 63;
  const float* W = (sel == 0) ? Wq : (sel == 1 ? Wk : Wv);
  float v = W[k * NH + h];
  if (sel == 0) v *= 0.125f * 1.44269504088896f;  // H^-0.5 * log2(e)
  Wt[idx] = (__bf16)v;
}

// ---- kernel 2: QKV projection, entire Wt in LDS (XOR-swizzled), x prefetched 4 deep.
__launch_bounds__(1024, 4)
__global__ void qkv_kernel(const float* __restrict__ x, const __bf16* __restrict__ Wt,
                           __bf16* __restrict__ Q, __bf16* __restrict__ K,
                           __bf16* __restrict__ Vt) {
  __shared__ __bf16 Wl[192 * 384];  // 147,456 B; chunk c of row r stored at c^(r&7)

  const int tid  = threadIdx.x;
  const int lane = tid & 63, wq = tid >> 6;
  const int quad = lane >> 4, l16 = lane & 15;
  const int rowblk = blockIdx.x * 256;
  const int rbase  = rowblk + wq * 16;
  const int row    = rbase + l16;

  // stage Wt -> LDS, 16-B chunks, XOR swizzle
  #pragma unroll
  for (int i = 0; i < 9; ++i) {
    int g = tid + i * 1024;
    int r = g / 48, c = g - r * 48;
    int p = c ^ (r & 7);
    uint4 v = ((const uint4*)Wt)[g];
    *(uint4*)&Wl[(r * 48 + p) * 8] = v;
  }
  __syncthreads();

  f32x4 acc[12];
  #pragma unroll
  for (int n = 0; n < 12; ++n) acc[n] = f32x4{0.f, 0.f, 0.f, 0.f};

  const float* xrow = x + (size_t)row * NC;
  f32x4 xp0[4], xp1[4];
  #pragma unroll
  for (int d = 0; d < 4; ++d) {  // 4-deep prefetch pipeline
    xp0[d] = *(const f32x4*)(xrow + d * 32 + quad * 8);
    xp1[d] = *(const f32x4*)(xrow + d * 32 + quad * 8 + 4);
  }

  #pragma unroll
  for (int kc = 0; kc < 12; ++kc) {
    const int slot = kc & 3;
    bf16_8 a;
    a[0] = (__bf16)xp0[slot][0]; a[1] = (__bf16)xp0[slot][1];
    a[2] = (__bf16)xp0[slot][2]; a[3] = (__bf16)xp0[slot][3];
    a[4] = (__bf16)xp1[slot][0]; a[5] = (__bf16)xp1[slot][1];
    a[6] = (__bf16)xp1[slot][2]; a[7] = (__bf16)xp1[slot][3];
    if (kc + 4 < 12) {  // refill slot, 4 iterations ahead
      const float* xp = xrow + (kc + 4) * 32 + quad * 8;
      xp0[slot] = *(const f32x4*)xp;
      xp1[slot] = *(const f32x4*)(xp + 4);
    }
    const int pc = (kc * 4 + quad) ^ (l16 & 7);
    const int cbase = l16 * 48 + pc;
    #pragma unroll
    for (int n = 0; n < 12; ++n) {
      bf16_8 b = *(const bf16_8*)&Wl[(n * 16 * 48 + cbase) * 8];
      acc[n] = mfma16(a, b, acc[n]);
    }
  }

  // Q, K direct stores (C-layout: row=quad*4+r, col=l16)
  #pragma unroll
  for (int n = 0; n < 8; ++n)
    #pragma unroll
    for (int r = 0; r < 4; ++r) {
      int orow = rbase + quad * 4 + r;
      int h = (n & 3) * 16 + l16;
      __bf16 bv = (__bf16)acc[n][r];
      if (n < 4) Q[(size_t)orow * NH + h] = bv;
      else       K[(size_t)orow * NH + h] = bv;
    }

  // V transpose via reused W LDS region
  __syncthreads();
  __bf16 (*Vl)[264] = (__bf16(*)[264])Wl;  // [h][t_local 256 + pad8]
  #pragma unroll
  for (int n = 8; n < 12; ++n) {
    int h = (n - 8) * 16 + l16;
    int t0 = wq * 16 + quad * 4;
    bf16_4 p;
    p[0] = (__bf16)acc[n][0]; p[1] = (__bf16)acc[n][1];
    p[2] = (__bf16)acc[n][2]; p[3] = (__bf16)acc[n][3];
    *(bf16_4*)&Vl[h][t0] = p;
  }
  __syncthreads();
  {
    int h = tid >> 4, seg = tid & 15;
    int bb = rowblk >> 11, t0 = (rowblk & (NT - 1)) + seg * 16;
    const __bf16* src = &Vl[h][seg * 16];
    __bf16* dst = Vt + ((size_t)(bb * NH + h)) * NT + t0;
    ((uint4*)dst)[0] = ((const uint4*)src)[0];
    ((uint4*)dst)[1] = ((const uint4*)src)[1];
  }
}

// ---- kernel 3: flash attention. 512 threads (8 waves), BM=128, BN=128.
// Grid = 32 batches x 8 pairs = 256 blocks = 1/CU. Block p does q-positions
// {15-p, p} (128 q each) -> exactly 17 super-iterations per block.
// Staging: 32 B K + 32 B V per thread (16 VGPRs) -> no spill (round-5 lesson:
// 32-reg prefetch + 128-VGPR occupancy cap = 200 MB scratch traffic).
__launch_bounds__(512, 2)
__global__ void attn_kernel(const __bf16* __restrict__ Q, const __bf16* __restrict__ K,
                            const __bf16* __restrict__ Vt, float* __restrict__ out) {
  __shared__ __bf16 Ks[128][72];     // [s][h]
  __shared__ __bf16 Vs[64][136];     // [h][s]
  __shared__ __bf16 Ps[8][16][136];  // per-wave P[q][s 128]

  const int tid  = threadIdx.x;
  const int lane = tid & 63, wq = tid >> 6;
  const int quad = lane >> 4, l16 = lane & 15;
  const int b    = blockIdx.x >> 3;
  const int pair = blockIdx.x & 7;

  const float NEG_INF = -__builtin_inff();
  // staging split: K tile 128x64 (4 thr/row, 32 B each), V tile 64x128 (8 thr/row)
  const int kr = tid >> 2, kc = (tid & 3) * 16;
  const int vr = tid >> 3, vc = (tid & 7) * 16;
  const __bf16* Kg = K  + (size_t)b * NT * NH;
  const __bf16* Vg = Vt + (size_t)b * NH * NT;

  for (int pass = 0; pass < 2; ++pass) {
    const int jpos = pass ? pair : (15 - pair);
    const int q0 = jpos * 128;
    const int nSuper = jpos + 1;

    const __bf16* qrow = Q + ((size_t)(b * NT + q0 + wq * 16 + l16)) * NH + quad * 8;
    bf16_8 qf0 = *(const bf16_8*)qrow;
    bf16_8 qf1 = *(const bf16_8*)(qrow + 32);

    f32x4 o[4];
    #pragma unroll
    for (int i = 0; i < 4; ++i) o[i] = f32x4{0.f, 0.f, 0.f, 0.f};
    float m_i = NEG_INF, l_i = 0.f;

    // prologue: stage super-tile 0 (prev pass's readers done at its final barrier)
    {
      const uint4* kp = (const uint4*)(Kg + (size_t)kr * NH + kc);
      uint4 k0 = kp[0], k1 = kp[1];
      const uint4* vp = (const uint4*)(Vg + (size_t)vr * NT + vc);
      uint4 v0 = vp[0], v1 = vp[1];
      *(uint4*)&Ks[kr][kc]     = k0; *(uint4*)&Ks[kr][kc + 8] = k1;
      *(uint4*)&Vs[vr][vc]     = v0; *(uint4*)&Vs[vr][vc + 8] = v1;
    }

    for (int i = 0; i < nSuper; ++i) {
      const bool more = (i + 1 < nSuper);
      const bool diag = (i == nSuper - 1);
      uint4 pk[2], pv[2];
      if (more) {  // issue next super-tile's loads; in flight across both barriers
        const int s0n = (i + 1) * 128;
        const uint4* kp = (const uint4*)(Kg + (size_t)(s0n + kr) * NH + kc);
        pk[0] = kp[0]; pk[1] = kp[1];
        const uint4* vp = (const uint4*)(Vg + (size_t)vr * NT + s0n + vc);
        pv[0] = vp[0]; pv[1] = vp[1];
      }
      __syncthreads();  // current super-tile fully staged

      // S^T: A=K rows (m=s), B=Q^T (n=q). 8 s-subtiles of 16.
      // Diagonal super: subtiles beyond this wave's q range are fully masked -> skip MFMA.
      const int stMax = diag ? (wq + 1) : 8;
      f32x4 sv[8];
      #pragma unroll
      for (int st = 0; st < 8; ++st) {
        if (st < stMax) {
          bf16_8 a0 = *(const bf16_8*)&Ks[st * 16 + l16][quad * 8];
          bf16_8 a1 = *(const bf16_8*)&Ks[st * 16 + l16][quad * 8 + 32];
          f32x4 accv = f32x4{0.f, 0.f, 0.f, 0.f};
          accv = mfma16(a0, qf0, accv);
          accv = mfma16(a1, qf1, accv);
          sv[st] = accv;
        } else {
          sv[st] = f32x4{NEG_INF, NEG_INF, NEG_INF, NEG_INF};
        }
      }

      if (diag) {  // partial causal mask inside the live subtiles (q-local = wq*16+l16)
        int slimit = wq * 16 + l16;
        #pragma unroll
        for (int st = 0; st < 8; ++st)
          if (st < stMax)
            #pragma unroll
            for (int rr = 0; rr < 4; ++rr) {
              int sloc = st * 16 + quad * 4 + rr;
              if (sloc > slimit) sv[st][rr] = NEG_INF;
            }
      }

      // online softmax in exp2 domain (log2e pre-folded into Wq)
      float mx = NEG_INF;
      #pragma unroll
      for (int st = 0; st < 8; ++st)
        #pragma unroll
        for (int rr = 0; rr < 4; ++rr) mx = fmaxf(mx, sv[st][rr]);
      mx = fmaxf(mx, __shfl_xor(mx, 16));
      mx = fmaxf(mx, __shfl_xor(mx, 32));
      float m_new = fmaxf(m_i, mx);
      float alpha = __builtin_amdgcn_exp2f(m_i - m_new);

      float lsum = 0.f;
      #pragma unroll
      for (int st = 0; st < 8; ++st) {
        bf16_4 pkv;
        #pragma unroll
        for (int rr = 0; rr < 4; ++rr) {
          float p = __builtin_amdgcn_exp2f(sv[st][rr] - m_new);
          lsum += p;
          pkv[rr] = (__bf16)p;
        }
        *(bf16_4*)&Ps[wq][l16][st * 16 + quad * 4] = pkv;
      }
      lsum += __shfl_xor(lsum, 16);
      lsum += __shfl_xor(lsum, 32);
      l_i = l_i * alpha + lsum;
      m_i = m_new;

      // rescale O (C-layout row q = quad*4+rr)
      f32x4 av;
      #pragma unroll
      for (int rr = 0; rr < 4; ++rr) av[rr] = __shfl(alpha, quad * 4 + rr);
      #pragma unroll
      for (int nt = 0; nt < 4; ++nt)
        #pragma unroll
        for (int rr = 0; rr < 4; ++rr) o[nt][rr] *= av[rr];

      // PV over k=128: A = P (own wave's Ps), B = V. Diagonal: skip all-zero k-blocks.
      const int cMax = diag ? ((wq >> 1) + 1) : 4;
      #pragma unroll
      for (int c = 0; c < 4; ++c) {
        if (c < cMax) {
          bf16_8 pa = *(const bf16_8*)&Ps[wq][l16][c * 32 + quad * 8];
          #pragma unroll
          for (int nt = 0; nt < 4; ++nt) {
            bf16_8 bv = *(const bf16_8*)&Vs[nt * 16 + l16][c * 32 + quad * 8];
            o[nt] = mfma16(pa, bv, o[nt]);
          }
        }
      }

      __syncthreads();  // all readers done with current super-tile
      if (more) {
        *(uint4*)&Ks[kr][kc]     = pk[0]; *(uint4*)&Ks[kr][kc + 8] = pk[1];
        *(uint4*)&Vs[vr][vc]     = pv[0]; *(uint4*)&Vs[vr][vc + 8] = pv[1];
      }
    }

    // epilogue: divide by l, store fp32
    f32x4 lv;
    #pragma unroll
    for (int rr = 0; rr < 4; ++rr) lv[rr] = 1.f / __shfl(l_i, quad * 4 + rr);
    float* op = out + ((size_t)(b * NT + q0 + wq * 16 + quad * 4)) * NH + l16;
    #pragma unroll
    for (int nt = 0; nt < 4; ++nt)
      #pragma unroll
      for (int rr = 0; rr < 4; ++rr)
        op[(size_t)rr * NH + nt * 16] = o[nt][rr] * lv[rr];
  }
}

extern "C" void kernel_launch(void* const* d_in, const int* in_sizes, int n_in,
                              void* d_out, int out_size, void* d_ws, size_t ws_size,
                              hipStream_t stream) {
  const float* x  = (const float*)d_in[0];
  const float* Wk = (const float*)d_in[1];
  const float* Wq = (const float*)d_in[2];
  const float* Wv = (const float*)d_in[3];
  float* out = (float*)d_out;

  char* ws = (char*)d_ws;
  __bf16* Wt  = (__bf16*)ws;                       // 192*384*2 = 147,456 B
  __bf16* Qb  = (__bf16*)(ws + 256 * 1024);        // each 32*2048*64*2 = 8 MiB
  __bf16* Kb  = Qb + (size_t)NB * NT * NH;
  __bf16* Vtb = Kb + (size_t)NB * NT * NH;

  pack_w_kernel<<<288, 256, 0, stream>>>(Wk, Wq, Wv, Wt);
  qkv_kernel<<<256, 1024, 0, stream>>>(x, Wt, Qb, Kb, Vtb);
  attn_kernel<<<NB * 8, 512, 0, stream>>>(Qb, Kb, Vtb, out);
}

// Round 7
// 237.746 us; speedup vs baseline: 1.0841x; 1.0080x over previous
//
#include <hip/hip_runtime.h>

typedef __bf16 bf16_8 __attribute__((ext_vector_type(8)));
typedef __bf16 bf16_4 __attribute__((ext_vector_type(4)));
typedef float  f32x4  __attribute__((ext_vector_type(4)));

#define NB 32
#define NT 2048
#define NC 384
#define NH 64

static __device__ __forceinline__ f32x4 mfma16(bf16_8 a, bf16_8 b, f32x4 c) {
  return __builtin_amdgcn_mfma_f32_16x16x32_bf16(a, b, c, 0, 0, 0);
}

// ---- kernel 1: pack weights: fp32 [C,H] x3 -> bf16 Wt[n][k], n: 0-63=Q, 64-127=K, 128-191=V
// Q gets 0.125*log2(e) folded in: attention softmax then runs in exp2 domain.
__global__ void pack_w_kernel(const float* __restrict__ Wk, const float* __restrict__ Wq,
                              const float* __restrict__ Wv, __bf16* __restrict__ Wt) {
  int idx = blockIdx.x * 256 + threadIdx.x;
  if (idx >= 192 * NC) return;
  int n = idx / NC, k = idx % NC;
  int sel = n >> 6, h = n & 63;
  const float* W = (sel == 0) ? Wq : (sel == 1 ? Wk : Wv);
  float v = W[k * NH + h];
  if (sel == 0) v *= 0.125f * 1.44269504088896f;  // H^-0.5 * log2(e)
  Wt[idx] = (__bf16)v;
}

// ---- kernel 2: QKV projection, entire Wt in LDS (XOR-swizzled), x prefetched 4 deep.
__launch_bounds__(1024, 4)
__global__ void qkv_kernel(const float* __restrict__ x, const __bf16* __restrict__ Wt,
                           __bf16* __restrict__ Q, __bf16* __restrict__ K,
                           __bf16* __restrict__ Vt) {
  __shared__ __bf16 Wl[192 * 384];  // 147,456 B; chunk c of row r stored at c^(r&7)

  const int tid  = threadIdx.x;
  const int lane = tid & 63, wq = tid >> 6;
  const int quad = lane >> 4, l16 = lane & 15;
  const int rowblk = blockIdx.x * 256;
  const int rbase  = rowblk + wq * 16;
  const int row    = rbase + l16;

  // stage Wt -> LDS, 16-B chunks, XOR swizzle
  #pragma unroll
  for (int i = 0; i < 9; ++i) {
    int g = tid + i * 1024;
    int r = g / 48, c = g - r * 48;
    int p = c ^ (r & 7);
    uint4 v = ((const uint4*)Wt)[g];
    *(uint4*)&Wl[(r * 48 + p) * 8] = v;
  }
  __syncthreads();

  f32x4 acc[12];
  #pragma unroll
  for (int n = 0; n < 12; ++n) acc[n] = f32x4{0.f, 0.f, 0.f, 0.f};

  const float* xrow = x + (size_t)row * NC;
  f32x4 xp0[4], xp1[4];
  #pragma unroll
  for (int d = 0; d < 4; ++d) {  // 4-deep prefetch pipeline
    xp0[d] = *(const f32x4*)(xrow + d * 32 + quad * 8);
    xp1[d] = *(const f32x4*)(xrow + d * 32 + quad * 8 + 4);
  }

  #pragma unroll
  for (int kc = 0; kc < 12; ++kc) {
    const int slot = kc & 3;
    bf16_8 a;
    a[0] = (__bf16)xp0[slot][0]; a[1] = (__bf16)xp0[slot][1];
    a[2] = (__bf16)xp0[slot][2]; a[3] = (__bf16)xp0[slot][3];
    a[4] = (__bf16)xp1[slot][0]; a[5] = (__bf16)xp1[slot][1];
    a[6] = (__bf16)xp1[slot][2]; a[7] = (__bf16)xp1[slot][3];
    if (kc + 4 < 12) {  // refill slot, 4 iterations ahead
      const float* xp = xrow + (kc + 4) * 32 + quad * 8;
      xp0[slot] = *(const f32x4*)xp;
      xp1[slot] = *(const f32x4*)(xp + 4);
    }
    const int pc = (kc * 4 + quad) ^ (l16 & 7);
    const int cbase = l16 * 48 + pc;
    #pragma unroll
    for (int n = 0; n < 12; ++n) {
      bf16_8 b = *(const bf16_8*)&Wl[(n * 16 * 48 + cbase) * 8];
      acc[n] = mfma16(a, b, acc[n]);
    }
  }

  // Q, K direct stores (C-layout: row=quad*4+r, col=l16)
  #pragma unroll
  for (int n = 0; n < 8; ++n)
    #pragma unroll
    for (int r = 0; r < 4; ++r) {
      int orow = rbase + quad * 4 + r;
      int h = (n & 3) * 16 + l16;
      __bf16 bv = (__bf16)acc[n][r];
      if (n < 4) Q[(size_t)orow * NH + h] = bv;
      else       K[(size_t)orow * NH + h] = bv;
    }

  // V transpose via reused W LDS region
  __syncthreads();
  __bf16 (*Vl)[264] = (__bf16(*)[264])Wl;  // [h][t_local 256 + pad8]
  #pragma unroll
  for (int n = 8; n < 12; ++n) {
    int h = (n - 8) * 16 + l16;
    int t0 = wq * 16 + quad * 4;
    bf16_4 p;
    p[0] = (__bf16)acc[n][0]; p[1] = (__bf16)acc[n][1];
    p[2] = (__bf16)acc[n][2]; p[3] = (__bf16)acc[n][3];
    *(bf16_4*)&Vl[h][t0] = p;
  }
  __syncthreads();
  {
    int h = tid >> 4, seg = tid & 15;
    int bb = rowblk >> 11, t0 = (rowblk & (NT - 1)) + seg * 16;
    const __bf16* src = &Vl[h][seg * 16];
    __bf16* dst = Vt + ((size_t)(bb * NH + h)) * NT + t0;
    ((uint4*)dst)[0] = ((const uint4*)src)[0];
    ((uint4*)dst)[1] = ((const uint4*)src)[1];
  }
}

// ---- kernel 3: flash attention. 512 threads (8 waves), BM=128, BN=128.
// Grid = 512 blocks = 2 independent blocks/CU (round-6 lesson: 1 block/CU
// phase-locks all waves at the barriers -> every pipe <20%). One q-position
// per block; blocks i and i+256 share a CU under round-robin, so i<256 gets
// the heavy position (15-pair) and i>=256 the light one (pair): 17 supers/CU
// in two independent barrier domains.
__launch_bounds__(512, 2)
__global__ void attn_kernel(const __bf16* __restrict__ Q, const __bf16* __restrict__ K,
                            const __bf16* __restrict__ Vt, float* __restrict__ out) {
  __shared__ __bf16 Ks[128][72];     // [s][h]
  __shared__ __bf16 Vs[64][136];     // [h][s]
  __shared__ __bf16 Ps[8][16][136];  // per-wave P[q][s 128]

  const int tid  = threadIdx.x;
  const int lane = tid & 63, wq = tid >> 6;
  const int quad = lane >> 4, l16 = lane & 15;
  const int jb   = blockIdx.x & 255;
  const int b    = jb >> 3;
  const int pair = jb & 7;
  const int jpos = (blockIdx.x < 256) ? (15 - pair) : pair;
  const int q0 = jpos * 128;
  const int nSuper = jpos + 1;

  const float NEG_INF = -__builtin_inff();
  // staging split: K tile 128x64 (4 thr/row, 32 B each), V tile 64x128 (8 thr/row)
  const int kr = tid >> 2, kc = (tid & 3) * 16;
  const int vr = tid >> 3, vc = (tid & 7) * 16;
  const __bf16* Kg = K  + (size_t)b * NT * NH;
  const __bf16* Vg = Vt + (size_t)b * NH * NT;

  const __bf16* qrow = Q + ((size_t)(b * NT + q0 + wq * 16 + l16)) * NH + quad * 8;
  bf16_8 qf0 = *(const bf16_8*)qrow;
  bf16_8 qf1 = *(const bf16_8*)(qrow + 32);

  f32x4 o[4];
  #pragma unroll
  for (int i = 0; i < 4; ++i) o[i] = f32x4{0.f, 0.f, 0.f, 0.f};
  float m_i = NEG_INF, l_i = 0.f;

  // prologue: stage super-tile 0
  {
    const uint4* kp = (const uint4*)(Kg + (size_t)kr * NH + kc);
    uint4 k0 = kp[0], k1 = kp[1];
    const uint4* vp = (const uint4*)(Vg + (size_t)vr * NT + vc);
    uint4 v0 = vp[0], v1 = vp[1];
    *(uint4*)&Ks[kr][kc]     = k0; *(uint4*)&Ks[kr][kc + 8] = k1;
    *(uint4*)&Vs[vr][vc]     = v0; *(uint4*)&Vs[vr][vc + 8] = v1;
  }

  for (int i = 0; i < nSuper; ++i) {
    const bool more = (i + 1 < nSuper);
    const bool diag = (i == nSuper - 1);
    uint4 pk[2], pv[2];
    if (more) {  // issue next super-tile's loads early
      const int s0n = (i + 1) * 128;
      const uint4* kp = (const uint4*)(Kg + (size_t)(s0n + kr) * NH + kc);
      pk[0] = kp[0]; pk[1] = kp[1];
      const uint4* vp = (const uint4*)(Vg + (size_t)vr * NT + s0n + vc);
      pv[0] = vp[0]; pv[1] = vp[1];
    }
    __syncthreads();  // current super-tile fully staged

    // S^T: A=K rows (m=s), B=Q^T (n=q). 8 s-subtiles of 16.
    // Diagonal super: subtiles beyond this wave's q range are fully masked -> skip MFMA.
    const int stMax = diag ? (wq + 1) : 8;
    f32x4 sv[8];
    #pragma unroll
    for (int st = 0; st < 8; ++st) {
      if (st < stMax) {
        bf16_8 a0 = *(const bf16_8*)&Ks[st * 16 + l16][quad * 8];
        bf16_8 a1 = *(const bf16_8*)&Ks[st * 16 + l16][quad * 8 + 32];
        f32x4 accv = f32x4{0.f, 0.f, 0.f, 0.f};
        accv = mfma16(a0, qf0, accv);
        accv = mfma16(a1, qf1, accv);
        sv[st] = accv;
      } else {
        sv[st] = f32x4{NEG_INF, NEG_INF, NEG_INF, NEG_INF};
      }
    }

    if (diag) {  // partial causal mask inside the live subtiles (q-local = wq*16+l16)
      int slimit = wq * 16 + l16;
      #pragma unroll
      for (int st = 0; st < 8; ++st)
        if (st < stMax)
          #pragma unroll
          for (int rr = 0; rr < 4; ++rr) {
            int sloc = st * 16 + quad * 4 + rr;
            if (sloc > slimit) sv[st][rr] = NEG_INF;
          }
    }

    // online softmax in exp2 domain (log2e pre-folded into Wq)
    float mx = NEG_INF;
    #pragma unroll
    for (int st = 0; st < 8; ++st)
      #pragma unroll
      for (int rr = 0; rr < 4; ++rr) mx = fmaxf(mx, sv[st][rr]);
    mx = fmaxf(mx, __shfl_xor(mx, 16));
    mx = fmaxf(mx, __shfl_xor(mx, 32));
    float m_new = fmaxf(m_i, mx);
    float alpha = __builtin_amdgcn_exp2f(m_i - m_new);

    float lsum = 0.f;
    #pragma unroll
    for (int st = 0; st < 8; ++st) {
      bf16_4 pkv;
      #pragma unroll
      for (int rr = 0; rr < 4; ++rr) {
        float p = __builtin_amdgcn_exp2f(sv[st][rr] - m_new);
        lsum += p;
        pkv[rr] = (__bf16)p;
      }
      *(bf16_4*)&Ps[wq][l16][st * 16 + quad * 4] = pkv;
    }
    lsum += __shfl_xor(lsum, 16);
    lsum += __shfl_xor(lsum, 32);
    l_i = l_i * alpha + lsum;
    m_i = m_new;

    // rescale O (C-layout row q = quad*4+rr)
    f32x4 av;
    #pragma unroll
    for (int rr = 0; rr < 4; ++rr) av[rr] = __shfl(alpha, quad * 4 + rr);
    #pragma unroll
    for (int nt = 0; nt < 4; ++nt)
      #pragma unroll
      for (int rr = 0; rr < 4; ++rr) o[nt][rr] *= av[rr];

    // PV over k=128: A = P (own wave's Ps), B = V. Diagonal: skip all-zero k-blocks.
    const int cMax = diag ? ((wq >> 1) + 1) : 4;
    #pragma unroll
    for (int c = 0; c < 4; ++c) {
      if (c < cMax) {
        bf16_8 pa = *(const bf16_8*)&Ps[wq][l16][c * 32 + quad * 8];
        #pragma unroll
        for (int nt = 0; nt < 4; ++nt) {
          bf16_8 bv = *(const bf16_8*)&Vs[nt * 16 + l16][c * 32 + quad * 8];
          o[nt] = mfma16(pa, bv, o[nt]);
        }
      }
    }

    __syncthreads();  // all readers done with current super-tile
    if (more) {
      *(uint4*)&Ks[kr][kc]     = pk[0]; *(uint4*)&Ks[kr][kc + 8] = pk[1];
      *(uint4*)&Vs[vr][vc]     = pv[0]; *(uint4*)&Vs[vr][vc + 8] = pv[1];
    }
  }

  // epilogue: divide by l, store fp32
  f32x4 lv;
  #pragma unroll
  for (int rr = 0; rr < 4; ++rr) lv[rr] = 1.f / __shfl(l_i, quad * 4 + rr);
  float* op = out + ((size_t)(b * NT + q0 + wq * 16 + quad * 4)) * NH + l16;
  #pragma unroll
  for (int nt = 0; nt < 4; ++nt)
    #pragma unroll
    for (int rr = 0; rr < 4; ++rr)
      op[(size_t)rr * NH + nt * 16] = o[nt][rr] * lv[rr];
}

extern "C" void kernel_launch(void* const* d_in, const int* in_sizes, int n_in,
                              void* d_out, int out_size, void* d_ws, size_t ws_size,
                              hipStream_t stream) {
  const float* x  = (const float*)d_in[0];
  const float* Wk = (const float*)d_in[1];
  const float* Wq = (const float*)d_in[2];
  const float* Wv = (const float*)d_in[3];
  float* out = (float*)d_out;

  char* ws = (char*)d_ws;
  __bf16* Wt  = (__bf16*)ws;                       // 192*384*2 = 147,456 B
  __bf16* Qb  = (__bf16*)(ws + 256 * 1024);        // each 32*2048*64*2 = 8 MiB
  __bf16* Kb  = Qb + (size_t)NB * NT * NH;
  __bf16* Vtb = Kb + (size_t)NB * NT * NH;

  pack_w_kernel<<<288, 256, 0, stream>>>(Wk, Wq, Wv, Wt);
  qkv_kernel<<<256, 1024, 0, stream>>>(x, Wt, Qb, Kb, Vtb);
  attn_kernel<<<NB * 16, 512, 0, stream>>>(Qb, Kb, Vtb, out);
}

// Round 8
// 212.084 us; speedup vs baseline: 1.2153x; 1.1210x over previous
//
#include <hip/hip_runtime.h>

typedef __bf16 bf16_8 __attribute__((ext_vector_type(8)));
typedef __bf16 bf16_4 __attribute__((ext_vector_type(4)));
typedef float  f32x4  __attribute__((ext_vector_type(4)));

#define NB 32
#define NT 2048
#define NC 384
#define NH 64

static __device__ __forceinline__ f32x4 mfma16(bf16_8 a, bf16_8 b, f32x4 c) {
  return __builtin_amdgcn_mfma_f32_16x16x32_bf16(a, b, c, 0, 0, 0);
}

// ---- kernel 1: pack weights: fp32 [C,H] x3 -> bf16 Wt[n][k], n: 0-63=Q, 64-127=K, 128-191=V
// Q gets 0.125*log2(e) folded in: attention softmax then runs in exp2 domain.
__global__ void pack_w_kernel(const float* __restrict__ Wk, const float* __restrict__ Wq,
                              const float* __restrict__ Wv, __bf16* __restrict__ Wt) {
  int idx = blockIdx.x * 256 + threadIdx.x;
  if (idx >= 192 * NC) return;
  int n = idx / NC, k = idx % NC;
  int sel = n >> 6, h = n & 63;
  const float* W = (sel == 0) ? Wq : (sel == 1 ? Wk : Wv);
  float v = W[k * NH + h];
  if (sel == 0) v *= 0.125f * 1.44269504088896f;  // H^-0.5 * log2(e)
  Wt[idx] = (__bf16)v;
}

// ---- kernel 2: QKV projection, entire Wt in LDS (XOR-swizzled), x prefetched 4 deep.
__launch_bounds__(1024, 4)
__global__ void qkv_kernel(const float* __restrict__ x, const __bf16* __restrict__ Wt,
                           __bf16* __restrict__ Q, __bf16* __restrict__ K,
                           __bf16* __restrict__ Vt) {
  __shared__ __bf16 Wl[192 * 384];  // 147,456 B; chunk c of row r stored at c^(r&7)

  const int tid  = threadIdx.x;
  const int lane = tid & 63, wq = tid >> 6;
  const int quad = lane >> 4, l16 = lane & 15;
  const int rowblk = blockIdx.x * 256;
  const int rbase  = rowblk + wq * 16;
  const int row    = rbase + l16;

  // stage Wt -> LDS, 16-B chunks, XOR swizzle
  #pragma unroll
  for (int i = 0; i < 9; ++i) {
    int g = tid + i * 1024;
    int r = g / 48, c = g - r * 48;
    int p = c ^ (r & 7);
    uint4 v = ((const uint4*)Wt)[g];
    *(uint4*)&Wl[(r * 48 + p) * 8] = v;
  }
  __syncthreads();

  f32x4 acc[12];
  #pragma unroll
  for (int n = 0; n < 12; ++n) acc[n] = f32x4{0.f, 0.f, 0.f, 0.f};

  const float* xrow = x + (size_t)row * NC;
  f32x4 xp0[4], xp1[4];
  #pragma unroll
  for (int d = 0; d < 4; ++d) {  // 4-deep prefetch pipeline
    xp0[d] = *(const f32x4*)(xrow + d * 32 + quad * 8);
    xp1[d] = *(const f32x4*)(xrow + d * 32 + quad * 8 + 4);
  }

  #pragma unroll
  for (int kc = 0; kc < 12; ++kc) {
    const int slot = kc & 3;
    bf16_8 a;
    a[0] = (__bf16)xp0[slot][0]; a[1] = (__bf16)xp0[slot][1];
    a[2] = (__bf16)xp0[slot][2]; a[3] = (__bf16)xp0[slot][3];
    a[4] = (__bf16)xp1[slot][0]; a[5] = (__bf16)xp1[slot][1];
    a[6] = (__bf16)xp1[slot][2]; a[7] = (__bf16)xp1[slot][3];
    if (kc + 4 < 12) {  // refill slot, 4 iterations ahead
      const float* xp = xrow + (kc + 4) * 32 + quad * 8;
      xp0[slot] = *(const f32x4*)xp;
      xp1[slot] = *(const f32x4*)(xp + 4);
    }
    const int pc = (kc * 4 + quad) ^ (l16 & 7);
    const int cbase = l16 * 48 + pc;
    #pragma unroll
    for (int n = 0; n < 12; ++n) {
      bf16_8 b = *(const bf16_8*)&Wl[(n * 16 * 48 + cbase) * 8];
      acc[n] = mfma16(a, b, acc[n]);
    }
  }

  // Q, K direct stores (C-layout: row=quad*4+r, col=l16)
  #pragma unroll
  for (int n = 0; n < 8; ++n)
    #pragma unroll
    for (int r = 0; r < 4; ++r) {
      int orow = rbase + quad * 4 + r;
      int h = (n & 3) * 16 + l16;
      __bf16 bv = (__bf16)acc[n][r];
      if (n < 4) Q[(size_t)orow * NH + h] = bv;
      else       K[(size_t)orow * NH + h] = bv;
    }

  // V transpose via reused W LDS region
  __syncthreads();
  __bf16 (*Vl)[264] = (__bf16(*)[264])Wl;  // [h][t_local 256 + pad8]
  #pragma unroll
  for (int n = 8; n < 12; ++n) {
    int h = (n - 8) * 16 + l16;
    int t0 = wq * 16 + quad * 4;
    bf16_4 p;
    p[0] = (__bf16)acc[n][0]; p[1] = (__bf16)acc[n][1];
    p[2] = (__bf16)acc[n][2]; p[3] = (__bf16)acc[n][3];
    *(bf16_4*)&Vl[h][t0] = p;
  }
  __syncthreads();
  {
    int h = tid >> 4, seg = tid & 15;
    int bb = rowblk >> 11, t0 = (rowblk & (NT - 1)) + seg * 16;
    const __bf16* src = &Vl[h][seg * 16];
    __bf16* dst = Vt + ((size_t)(bb * NH + h)) * NT + t0;
    ((uint4*)dst)[0] = ((const uint4*)src)[0];
    ((uint4*)dst)[1] = ((const uint4*)src)[1];
  }
}

// ---- kernel 3: flash attention. 256 threads (4 waves), BM=64, BN=64.
// Every block runs two concatenated q-positions (31-p, then p): 33 tiles for
// ALL blocks -> grid 512 = 2 uniformly-busy blocks/CU for the whole kernel
// (round-7 lesson: pairing heavy+light blocks gives a 2nd barrier domain only
// 26% of the time). K/V double-buffered with ONE barrier per tile: between
// consecutive barriers readers touch buf[cur] and stagers touch buf[1-cur]
// only, so waves can skew across the whole tile body -> the LDS/VALU/MFMA
// phase storms de-phase instead of serializing (round-7: 10.8k cyc/super vs
// ~3k issue floor from phase-locking).
__launch_bounds__(256, 2)
__global__ void attn_kernel(const __bf16* __restrict__ Q, const __bf16* __restrict__ K,
                            const __bf16* __restrict__ Vt, float* __restrict__ out) {
  __shared__ __bf16 Ks[2][64][72];   // [buf][s][h]
  __shared__ __bf16 Vs[2][64][72];   // [buf][h][s]
  __shared__ __bf16 Ps[4][16][72];   // per-wave P[q][s 64]

  const int tid  = threadIdx.x;
  const int lane = tid & 63, wq = tid >> 6;
  const int quad = lane >> 4, l16 = lane & 15;
  const int b    = blockIdx.x >> 4;
  const int pr   = blockIdx.x & 15;

  const float NEG_INF = -__builtin_inff();
  // staging: 64x64 K tile and 64x64 V tile, 4 threads per 64-elem row (32 B each)
  const int sr = tid >> 2, sc = (tid & 3) * 16;
  const __bf16* Kg = K  + (size_t)b * NT * NH;
  const __bf16* Vg = Vt + (size_t)b * NH * NT;

  for (int pass = 0; pass < 2; ++pass) {
    const int jpos = pass ? pr : (31 - pr);
    const int q0 = jpos * 64;
    const int nT = jpos + 1;

    const __bf16* qrow = Q + ((size_t)(b * NT + q0 + wq * 16 + l16)) * NH + quad * 8;
    bf16_8 qf0 = *(const bf16_8*)qrow;
    bf16_8 qf1 = *(const bf16_8*)(qrow + 32);

    f32x4 o[4];
    #pragma unroll
    for (int i = 0; i < 4; ++i) o[i] = f32x4{0.f, 0.f, 0.f, 0.f};
    float m_i = NEG_INF, l_i = 0.f;

    __syncthreads();  // prev pass's readers done before restaging buf 0
    // prologue: stage tile 0 -> buf 0
    {
      const uint4* kp = (const uint4*)(Kg + (size_t)sr * NH + sc);
      uint4 k0 = kp[0], k1 = kp[1];
      const uint4* vp = (const uint4*)(Vg + (size_t)sr * NT + sc);
      uint4 v0 = vp[0], v1 = vp[1];
      *(uint4*)&Ks[0][sr][sc]     = k0; *(uint4*)&Ks[0][sr][sc + 8] = k1;
      *(uint4*)&Vs[0][sr][sc]     = v0; *(uint4*)&Vs[0][sr][sc + 8] = v1;
    }

    for (int i = 0; i < nT; ++i) {
      const int cur = i & 1;
      const bool more = (i + 1 < nT);
      const bool diag = (i == nT - 1);
      uint4 pk0, pk1, pv0, pv1;
      if (more) {  // next tile's global loads: in flight across the whole body
        const int s0n = (i + 1) * 64;
        const uint4* kp = (const uint4*)(Kg + (size_t)(s0n + sr) * NH + sc);
        pk0 = kp[0]; pk1 = kp[1];
        const uint4* vp = (const uint4*)(Vg + (size_t)sr * NT + s0n + sc);
        pv0 = vp[0]; pv1 = vp[1];
      }
      __syncthreads();  // tile i staged; buf[1-cur] free for restage

      // S^T: A=K rows (m=s), B=Q^T (n=q). 4 s-subtiles of 16, k=64.
      const int stMax = diag ? (wq + 1) : 4;  // beyond wave's q range: fully masked
      f32x4 sv[4];
      #pragma unroll
      for (int st = 0; st < 4; ++st) {
        if (st < stMax) {
          bf16_8 a0 = *(const bf16_8*)&Ks[cur][st * 16 + l16][quad * 8];
          bf16_8 a1 = *(const bf16_8*)&Ks[cur][st * 16 + l16][quad * 8 + 32];
          f32x4 accv = f32x4{0.f, 0.f, 0.f, 0.f};
          accv = mfma16(a0, qf0, accv);
          accv = mfma16(a1, qf1, accv);
          sv[st] = accv;
        } else {
          sv[st] = f32x4{NEG_INF, NEG_INF, NEG_INF, NEG_INF};
        }
      }

      if (diag) {  // causal mask inside live subtiles; q-local = wq*16+l16
        int slimit = wq * 16 + l16;
        #pragma unroll
        for (int st = 0; st < 4; ++st)
          if (st < stMax)
            #pragma unroll
            for (int rr = 0; rr < 4; ++rr) {
              int sloc = st * 16 + quad * 4 + rr;
              if (sloc > slimit) sv[st][rr] = NEG_INF;
            }
      }

      // online softmax in exp2 domain (log2e pre-folded into Wq)
      float mx = NEG_INF;
      #pragma unroll
      for (int st = 0; st < 4; ++st)
        #pragma unroll
        for (int rr = 0; rr < 4; ++rr) mx = fmaxf(mx, sv[st][rr]);
      mx = fmaxf(mx, __shfl_xor(mx, 16));
      mx = fmaxf(mx, __shfl_xor(mx, 32));
      float m_new = fmaxf(m_i, mx);
      float alpha = __builtin_amdgcn_exp2f(m_i - m_new);

      float lsum = 0.f;
      #pragma unroll
      for (int st = 0; st < 4; ++st) {
        bf16_4 pkv;
        #pragma unroll
        for (int rr = 0; rr < 4; ++rr) {
          float p = __builtin_amdgcn_exp2f(sv[st][rr] - m_new);
          lsum += p;
          pkv[rr] = (__bf16)p;
        }
        *(bf16_4*)&Ps[wq][l16][st * 16 + quad * 4] = pkv;
      }
      lsum += __shfl_xor(lsum, 16);
      lsum += __shfl_xor(lsum, 32);
      l_i = l_i * alpha + lsum;
      m_i = m_new;

      // restage next tile into buf[1-cur] (mid-body: vmcnt has had time to land)
      if (more) {
        *(uint4*)&Ks[1 - cur][sr][sc]     = pk0; *(uint4*)&Ks[1 - cur][sr][sc + 8] = pk1;
        *(uint4*)&Vs[1 - cur][sr][sc]     = pv0; *(uint4*)&Vs[1 - cur][sr][sc + 8] = pv1;
      }

      // rescale O (C-layout row q = quad*4+rr)
      f32x4 av;
      #pragma unroll
      for (int rr = 0; rr < 4; ++rr) av[rr] = __shfl(alpha, quad * 4 + rr);
      #pragma unroll
      for (int nt = 0; nt < 4; ++nt)
        #pragma unroll
        for (int rr = 0; rr < 4; ++rr) o[nt][rr] *= av[rr];

      // PV over k=64: A = P (own wave's Ps), B = V. Diagonal: skip all-zero k-blocks.
      const int cMax = diag ? ((wq >> 1) + 1) : 2;
      #pragma unroll
      for (int c = 0; c < 2; ++c) {
        if (c < cMax) {
          bf16_8 pa = *(const bf16_8*)&Ps[wq][l16][c * 32 + quad * 8];
          #pragma unroll
          for (int nt = 0; nt < 4; ++nt) {
            bf16_8 bv = *(const bf16_8*)&Vs[cur][nt * 16 + l16][c * 32 + quad * 8];
            o[nt] = mfma16(pa, bv, o[nt]);
          }
        }
      }
    }

    // epilogue: divide by l, store fp32
    f32x4 lv;
    #pragma unroll
    for (int rr = 0; rr < 4; ++rr) lv[rr] = 1.f / __shfl(l_i, quad * 4 + rr);
    float* op = out + ((size_t)(b * NT + q0 + wq * 16 + quad * 4)) * NH + l16;
    #pragma unroll
    for (int nt = 0; nt < 4; ++nt)
      #pragma unroll
      for (int rr = 0; rr < 4; ++rr)
        op[(size_t)rr * NH + nt * 16] = o[nt][rr] * lv[rr];
  }
}

extern "C" void kernel_launch(void* const* d_in, const int* in_sizes, int n_in,
                              void* d_out, int out_size, void* d_ws, size_t ws_size,
                              hipStream_t stream) {
  const float* x  = (const float*)d_in[0];
  const float* Wk = (const float*)d_in[1];
  const float* Wq = (const float*)d_in[2];
  const float* Wv = (const float*)d_in[3];
  float* out = (float*)d_out;

  char* ws = (char*)d_ws;
  __bf16* Wt  = (__bf16*)ws;                       // 192*384*2 = 147,456 B
  __bf16* Qb  = (__bf16*)(ws + 256 * 1024);        // each 32*2048*64*2 = 8 MiB
  __bf16* Kb  = Qb + (size_t)NB * NT * NH;
  __bf16* Vtb = Kb + (size_t)NB * NT * NH;

  pack_w_kernel<<<288, 256, 0, stream>>>(Wk, Wq, Wv, Wt);
  qkv_kernel<<<256, 1024, 0, stream>>>(x, Wt, Qb, Kb, Vtb);
  attn_kernel<<<NB * 16, 256, 0, stream>>>(Qb, Kb, Vtb, out);
}